// Round 7
// baseline (177.439 us; speedup 1.0000x reference)
//
#include <hip/hip_runtime.h>
#include <stdint.h>
#include <stddef.h>

#define SEQ 2048
#define DM  1024
#define NH  16
#define BS  2

typedef __attribute__((ext_vector_type(8)))  __bf16 bf16x8;
typedef __attribute__((ext_vector_type(4)))  __bf16 bf16x4;
typedef __attribute__((ext_vector_type(4)))  float  floatx4;
typedef __attribute__((ext_vector_type(16))) float  floatx16;
typedef __attribute__((ext_vector_type(4)))  unsigned int uintx4;
typedef __attribute__((ext_vector_type(4)))  unsigned short ushortx4;

#if __has_builtin(__builtin_amdgcn_exp2f)
#define EXP2(x) __builtin_amdgcn_exp2f(x)
#else
#define EXP2(x) __expf((x) * 0.6931471805599453f)
#endif

// 0.125 * log2(e): folded into Q at GEMM epilogue so attn does p = exp2(s)
#define QSCALE 0.18033688011112042f

#define GLDS(g, s) __builtin_amdgcn_global_load_lds( \
    (const __attribute__((address_space(1))) void*)(g), \
    (__attribute__((address_space(3))) void*)(s), 16, 0, 0)

__device__ inline unsigned short f2bf(float f) {
  union { float f; unsigned int u; } a; a.f = f;
  unsigned int u = a.u;
  return (unsigned short)((u + 0x7fffu + ((u >> 16) & 1u)) >> 16);  // RNE
}

__device__ inline bf16x8 ldb8(const unsigned short* p) { return *(const bf16x8*)p; }

// ---------------- fused prep: fp32->bf16 casts + fp32 mask01 ----------------
__global__ __launch_bounds__(256) void prep(
    const float* __restrict__ x, const float* __restrict__ wq,
    const float* __restrict__ wk, const float* __restrict__ wv,
    const int* __restrict__ mask,
    unsigned short* __restrict__ Xb, unsigned short* __restrict__ Wb,
    float* __restrict__ maskf) {
  const int bid = blockIdx.x, t = threadIdx.x;
  if (bid < 7168) {
    const float* src; unsigned short* dst; int base;
    if (bid < 4096)      { src = x;  dst = Xb;            base = bid; }
    else if (bid < 5120) { src = wq; dst = Wb;            base = bid - 4096; }
    else if (bid < 6144) { src = wk; dst = Wb + 1048576;  base = bid - 5120; }
    else                 { src = wv; dst = Wb + 2097152;  base = bid - 6144; }
    const int i = base * 256 + t;
    floatx4 v = ((const floatx4*)src)[i];
    ushortx4 o;
    o.x = f2bf(v.x); o.y = f2bf(v.y); o.z = f2bf(v.z); o.w = f2bf(v.w);
    ((ushortx4*)dst)[i] = o;
  } else {
    const int i = (bid - 7168) * 256 + t;   // 0..4095 = [b][key]
    maskf[i] = mask[i] ? 1.0f : 0.0f;
  }
}

// ---------------- QKV projection GEMM: C = X @ W^T + b ----------------
// 128x128 tile, BK=32 double-buffered, 1 barrier/iter prefetch pipeline.
// z=0 -> Qb (pre-scaled by QSCALE), z=1 -> Kb,
// z=2 -> Vt [b][h][d][seq] via LDS transpose, PRE-MASKED by mask[key]
__global__ __launch_bounds__(256, 3) void gemm_qkv(
    const unsigned short* __restrict__ Xb, const unsigned short* __restrict__ Wb,
    const float* __restrict__ bq, const float* __restrict__ bk, const float* __restrict__ bv,
    const int* __restrict__ mask,
    unsigned short* __restrict__ Qb, unsigned short* __restrict__ Kb,
    unsigned short* __restrict__ Vt)
{
  __shared__ alignas(16) unsigned short LB[16384];  // A dbuf @0/4096, B dbuf @8192/12288 (shorts)
  const int t = threadIdx.x;
  const int w = t >> 6, l = t & 63;
  const int lm = l & 15, lq = l >> 4;
  const int z = blockIdx.z;
  const size_t m0 = (size_t)blockIdx.y * 128;
  const size_t n0 = (size_t)blockIdx.x * 128;
  const unsigned short* W = Wb + (size_t)z * (1024 * 1024);
  const float* bias = (z == 0) ? bq : ((z == 1) ? bk : bv);
  const float sc = (z == 0) ? QSCALE : 1.0f;

  // staging: chunk c (16B) at LDS chunk-slot c; holds global (row=c>>2, kq=(c&3)^((row>>1)&3))
  const int c0 = t, c1 = 256 + t;
  const int row0 = c0 >> 2, row1 = c1 >> 2;
  const int kq0 = (c0 & 3) ^ ((row0 >> 1) & 3);
  const int kq1 = (c1 & 3) ^ ((row1 >> 1) & 3);
  const unsigned short* gA0 = Xb + (m0 + row0) * 1024 + kq0 * 8;
  const unsigned short* gA1 = Xb + (m0 + row1) * 1024 + kq1 * 8;
  const unsigned short* gB0 = W + (n0 + row0) * 1024 + kq0 * 8;
  const unsigned short* gB1 = W + (n0 + row1) * 1024 + kq1 * 8;
  const int la0 = (0 * 256 + w * 64) * 8;
  const int la1 = (1 * 256 + w * 64) * 8;

  const int wr = (w >> 1) * 64, wc = (w & 1) * 64;
  const int sw = (lq ^ ((lm >> 1) & 3)) * 8;
  floatx4 acc[4][4] = {};

  GLDS(gA0, LB + la0);
  GLDS(gA1, LB + la1);
  GLDS(gB0, LB + 8192 + la0);
  GLDS(gB1, LB + 8192 + la1);
  __syncthreads();

  for (int it = 0; it < 32; ++it) {
    const int cur = it & 1;
    if (it < 31) {
      const int kn = (it + 1) * 32;
      const int nb = (cur ^ 1) * 4096;
      GLDS(gA0 + kn, LB + nb + la0);
      GLDS(gA1 + kn, LB + nb + la1);
      GLDS(gB0 + kn, LB + 8192 + nb + la0);
      GLDS(gB1 + kn, LB + 8192 + nb + la1);
    }
    const unsigned short* Ab = LB + cur * 4096;
    const unsigned short* Bb = LB + 8192 + cur * 4096;
    bf16x8 af[4], bfr[4];
#pragma unroll
    for (int i = 0; i < 4; i++) af[i] = ldb8(Ab + (wr + i * 16 + lm) * 32 + sw);
#pragma unroll
    for (int j = 0; j < 4; j++) bfr[j] = ldb8(Bb + (wc + j * 16 + lm) * 32 + sw);
#pragma unroll
    for (int i = 0; i < 4; i++)
#pragma unroll
      for (int j = 0; j < 4; j++)
        acc[i][j] = __builtin_amdgcn_mfma_f32_16x16x32_bf16(af[i], bfr[j], acc[i][j], 0, 0, 0);
    __syncthreads();
  }

  // epilogue: C/D layout col=lane&15, row=quad*4+r
  if (z < 2) {
    unsigned short* dst = (z == 0) ? Qb : Kb;
#pragma unroll
    for (int j = 0; j < 4; j++) {
      const int ncol = (int)n0 + wc + j * 16 + lm;
      const float bval = bias[ncol];
#pragma unroll
      for (int i = 0; i < 4; i++)
#pragma unroll
        for (int r = 0; r < 4; r++) {
          const int mrow = (int)m0 + wr + i * 16 + lq * 4 + r;
          dst[(size_t)mrow * 1024 + ncol] = f2bf((acc[i][j][r] + bval) * sc);
        }
    }
  } else {
    // V: pre-mask rows by mask[key], transpose 128x128 through LDS, coalesced Vt stores
    float mk[4][4];
#pragma unroll
    for (int i = 0; i < 4; i++)
#pragma unroll
      for (int r = 0; r < 4; r++)
        mk[i][r] = (float)mask[(int)m0 + wr + i * 16 + lq * 4 + r];
#pragma unroll
    for (int j = 0; j < 4; j++) {
      const int nl = wc + j * 16 + lm;
      const float bval = bias[(int)n0 + nl];
#pragma unroll
      for (int i = 0; i < 4; i++)
#pragma unroll
        for (int r = 0; r < 4; r++) {
          const int ml = wr + i * 16 + lq * 4 + r;
          LB[nl * 128 + ((((ml >> 3) ^ (nl & 15)) * 8) | (ml & 7))] =
              f2bf((acc[i][j][r] + bval) * mk[i][r]);
        }
    }
    __syncthreads();
    const int nl = t >> 1, hf = t & 1;
    const int ncol = (int)n0 + nl;
    const int hh = ncol >> 6, dc = ncol & 63;
    const int bb = (int)(m0 >> 11);
    const int s0c = ((int)m0 & 2047) + hf * 64;
    unsigned short* dstp = Vt + (size_t)((bb * 16 + hh) * 64 + dc) * SEQ + s0c;
#pragma unroll
    for (int u = 0; u < 8; ++u) {
      const int phys = (hf * 8 + u) ^ (nl & 15);
      *(uintx4*)(dstp + u * 8) = *(const uintx4*)(LB + nl * 128 + phys * 8);
    }
  }
}

// ---------------- flash attention: 2-wave blocks, 4 barrier domains/CU ----------------
// grid 1024, block 128 (2 waves x 32 q = 64 q/block). pp=bid&31 -> (b,head): all
// q-blocks of a (b,h) land on XCD pp%8. LDS exactly 40960 B -> 4 blocks/CU, so a
// block draining its barrier leaves 3 independent blocks issuing. Mask folded into
// the exp2 pack from L2-hot fp32 loads; denominator via tacc += P·ones (const frag).
__global__ __launch_bounds__(128, 2) void attn(
    const unsigned short* __restrict__ Qb, const unsigned short* __restrict__ Kb,
    const unsigned short* __restrict__ Vt, const float* __restrict__ maskf,
    float* __restrict__ out)
{
  __shared__ alignas(16) unsigned short Klds[2][4096];  // [key][d], chunk-XOR (16 KB)
  __shared__ alignas(16) unsigned short Vlds[2][4096];  // [d][key], chunk-XOR (16 KB)
  __shared__ alignas(16) unsigned short Plds[2][2048];  // per-wave P (8 KB)

  const int t = threadIdx.x, w = t >> 6, l = t & 63;
  const int ln = l & 31, h = l >> 5;
  const int bid = blockIdx.x;
  const int pp = bid & 31;
  const int b = pp >> 4, head = pp & 15;
  const int q0w = (bid >> 5) * 64 + w * 32;
  const int hoff = head * 64;

  // staging: DMA id = w*4+s2 covers rows [id*8, id*8+8); lane l -> row id*8+(l>>3),
  // phys chunk l&7 holding global chunk (l&7)^(l>>3)
  const int sr = l >> 3;
  const int gc = (l & 7) ^ sr;
  const unsigned short* gK[4]; const unsigned short* gV[4];
#pragma unroll
  for (int s2 = 0; s2 < 4; ++s2) {
    const int row = w * 32 + s2 * 8 + sr;
    gK[s2] = Kb + (size_t)(b * SEQ + row) * DM + hoff + gc * 8;
    gV[s2] = Vt + (size_t)((b * NH + head) * 64 + row) * SEQ + gc * 8;
  }

  // stage tile 0 into buffer 0
#pragma unroll
  for (int s2 = 0; s2 < 4; ++s2) {
    GLDS(gK[s2], &Klds[0][(w * 4 + s2) * 512]);
    GLDS(gV[s2], &Vlds[0][(w * 4 + s2) * 512]);
  }

  // Q B-frags (n=q=ln, k=d)
  const unsigned short* Qbase = Qb + (size_t)(b * SEQ + q0w + ln) * DM + hoff + h * 8;
  bf16x8 qf[4];
#pragma unroll
  for (int c = 0; c < 4; ++c) qf[c] = ldb8(Qbase + c * 16);

  // frag-read swizzled chunk offsets: phys chunk = (2c+h) ^ (ln&7)
  const int cc = (ln >> 1) & 3, hb = h ^ (ln & 1);
  int xoff[4];
#pragma unroll
  for (int c = 0; c < 4; ++c) xoff[c] = (c ^ cc) * 16 + hb * 8;

  // constant all-ones B-frag for the denominator MFMA
  bf16x8 onef;
#pragma unroll
  for (int i = 0; i < 8; ++i) onef[i] = (__bf16)1.0f;

  const float* mbase = maskf + b * SEQ;
  unsigned short* Pw = &Plds[w][ln * 64];
  floatx16 oacc[2] = {};
  floatx16 tacc = {};   // denominator accumulator: rows match oacc rows

  __syncthreads();

  for (int kt = 0; kt < 32; ++kt) {
    const int cur = kt & 1;
    if (kt < 31) {   // prefetch next 64-key tile into the other buffer
      const int k0n = (kt + 1) * 64;
#pragma unroll
      for (int s2 = 0; s2 < 4; ++s2) {
        GLDS(gK[s2] + (size_t)k0n * DM, &Klds[cur ^ 1][(w * 4 + s2) * 512]);
        GLDS(gV[s2] + k0n,              &Vlds[cur ^ 1][(w * 4 + s2) * 512]);
      }
    }
    const unsigned short* Kc = &Klds[cur][ln * 64];
    const unsigned short* Vc = &Vlds[cur][ln * 64];

    bf16x8 kfr[8], vfr[8];
#pragma unroll
    for (int i = 0; i < 8; ++i) {
      kfr[i] = ldb8(Kc + (i >> 2) * 2048 + xoff[i & 3]);
      vfr[i] = ldb8(Vc + (i >> 2) * 2048 + xoff[i & 3]);
    }

    // S^T = K · Q^T  (rows=keys, cols=q)
    floatx16 s[2] = {};
#pragma unroll
    for (int c = 0; c < 4; ++c) {
      s[0] = __builtin_amdgcn_mfma_f32_32x32x16_bf16(kfr[c],     qf[c], s[0], 0, 0, 0);
      s[1] = __builtin_amdgcn_mfma_f32_32x32x16_bf16(kfr[4 + c], qf[c], s[1], 0, 0, 0);
    }

    // softmax numerators: p = exp2(s) * mask01 (masked keys -> exact 0).
    // C-layout: key_local = r + 8g + 4h, q = ln -> mask loads lane-uniform in ln.
    const int k0 = kt * 64;
#pragma unroll
    for (int kb = 0; kb < 2; ++kb)
#pragma unroll
      for (int g = 0; g < 4; ++g) {
        const floatx4 mkv = *(const floatx4*)(mbase + k0 + kb * 32 + g * 8 + h * 4);
        bf16x4 pk;
#pragma unroll
        for (int r = 0; r < 4; ++r) pk[r] = (__bf16)(EXP2(s[kb][g * 4 + r]) * mkv[r]);
        *(bf16x4*)(Pw + ((4 * kb + g) ^ (ln & 7)) * 8 + h * 4) = pk;
      }

    // P A-frags (wave-private LDS round trip, no barrier)
    bf16x8 pf[4];
#pragma unroll
    for (int c = 0; c < 4; ++c) pf[c] = ldb8(Pw + xoff[c]);

    // denominator: tacc += P · 1 (P already mask-zeroed; rows = q like oacc)
#pragma unroll
    for (int c = 0; c < 4; ++c)
      tacc = __builtin_amdgcn_mfma_f32_32x32x16_bf16(pf[c], onef, tacc, 0, 0, 0);

    // O += P · V (V pre-masked)
#pragma unroll
    for (int c = 0; c < 4; ++c) {
      oacc[0] = __builtin_amdgcn_mfma_f32_32x32x16_bf16(pf[c], vfr[c],     oacc[0], 0, 0, 0);
      oacc[1] = __builtin_amdgcn_mfma_f32_32x32x16_bf16(pf[c], vfr[4 + c], oacc[1], 0, 0, 0);
    }
    __syncthreads();   // drains prefetch issued one full tile of compute ago
  }

  // finalize: tacc[r] holds the denominator for row rq at every lane
  float* obase = out + (size_t)(b * SEQ + q0w) * DM + hoff;
#pragma unroll
  for (int r = 0; r < 16; ++r) {
    const int rq = (r & 3) + 8 * (r >> 2) + 4 * h;
    const float iv = __builtin_amdgcn_rcpf(tacc[r]);
    obase[(size_t)rq * DM + ln]      = oacc[0][r] * iv;
    obase[(size_t)rq * DM + 32 + ln] = oacc[1][r] * iv;
  }
}

// ---------------- launch ----------------
extern "C" void kernel_launch(void* const* d_in, const int* in_sizes, int n_in,
                              void* d_out, int out_size, void* d_ws, size_t ws_size,
                              hipStream_t stream) {
  const float* x   = (const float*)d_in[0];
  const int*   msk = (const int*)d_in[1];
  const float* Wq  = (const float*)d_in[2];
  const float* bq  = (const float*)d_in[3];
  const float* Wk  = (const float*)d_in[4];
  const float* bk  = (const float*)d_in[5];
  const float* Wv  = (const float*)d_in[6];
  const float* bv  = (const float*)d_in[7];
  float* out = (float*)d_out;

  unsigned short* ws = (unsigned short*)d_ws;
  unsigned short* Xb = ws;                               // [4096][1024]
  unsigned short* Wb = Xb + (size_t)4096 * 1024;         // [3][1024][1024]
  unsigned short* Qb = Wb + (size_t)3 * 1024 * 1024;     // [4096][1024], pre-scaled
  unsigned short* Kb = Qb + (size_t)4096 * 1024;         // [4096][1024]
  unsigned short* Vt = Kb + (size_t)4096 * 1024;         // [2][16][64][2048], pre-masked
  float* maskf = (float*)(Vt + (size_t)4096 * 1024);     // [2][2048] fp32 {0,1}

  prep<<<7184, 256, 0, stream>>>(x, Wq, Wk, Wv, msk, Xb, Wb, maskf);

  gemm_qkv<<<dim3(8, 32, 3), 256, 0, stream>>>(Xb, Wb, bq, bk, bv, msk, Qb, Kb, Vt);

  attn<<<1024, 128, 0, stream>>>(Qb, Kb, Vt, maskf, out);
}

// Round 8
// 164.548 us; speedup vs baseline: 1.0783x; 1.0783x over previous
//
#include <hip/hip_runtime.h>
#include <stdint.h>
#include <stddef.h>

#define SEQ 2048
#define DM  1024
#define NH  16
#define BS  2

typedef __attribute__((ext_vector_type(8)))  __bf16 bf16x8;
typedef __attribute__((ext_vector_type(4)))  __bf16 bf16x4;
typedef __attribute__((ext_vector_type(4)))  float  floatx4;
typedef __attribute__((ext_vector_type(16))) float  floatx16;
typedef __attribute__((ext_vector_type(4)))  unsigned int uintx4;
typedef __attribute__((ext_vector_type(4)))  unsigned short ushortx4;

#if __has_builtin(__builtin_amdgcn_exp2f)
#define EXP2(x) __builtin_amdgcn_exp2f(x)
#else
#define EXP2(x) __expf((x) * 0.6931471805599453f)
#endif

// 0.125 * log2(e): folded into Q at GEMM epilogue so attn does p = exp2(s)
#define QSCALE 0.18033688011112042f

#define GLDS(g, s) __builtin_amdgcn_global_load_lds( \
    (const __attribute__((address_space(1))) void*)(g), \
    (__attribute__((address_space(3))) void*)(s), 16, 0, 0)

__device__ inline unsigned short f2bf(float f) {
  union { float f; unsigned int u; } a; a.f = f;
  unsigned int u = a.u;
  return (unsigned short)((u + 0x7fffu + ((u >> 16) & 1u)) >> 16);  // RNE
}

__device__ inline bf16x8 ldb8(const unsigned short* p) { return *(const bf16x8*)p; }

// ---------------- fused prep: fp32->bf16 casts + bf16 mask01 ----------------
__global__ __launch_bounds__(256) void prep(
    const float* __restrict__ x, const float* __restrict__ wq,
    const float* __restrict__ wk, const float* __restrict__ wv,
    const int* __restrict__ mask,
    unsigned short* __restrict__ Xb, unsigned short* __restrict__ Wb,
    unsigned short* __restrict__ mb01) {
  const int bid = blockIdx.x, t = threadIdx.x;
  if (bid < 7168) {
    const float* src; unsigned short* dst; int base;
    if (bid < 4096)      { src = x;  dst = Xb;            base = bid; }
    else if (bid < 5120) { src = wq; dst = Wb;            base = bid - 4096; }
    else if (bid < 6144) { src = wk; dst = Wb + 1048576;  base = bid - 5120; }
    else                 { src = wv; dst = Wb + 2097152;  base = bid - 6144; }
    const int i = base * 256 + t;
    floatx4 v = ((const floatx4*)src)[i];
    ushortx4 o;
    o.x = f2bf(v.x); o.y = f2bf(v.y); o.z = f2bf(v.z); o.w = f2bf(v.w);
    ((ushortx4*)dst)[i] = o;
  } else {
    const int i = (bid - 7168) * 256 + t;   // 0..4095 = [b][key]
    mb01[i] = mask[i] ? 0x3F80 : 0;          // bf16 1.0 / 0.0
  }
}

// ---------------- QKV projection GEMM: C = X @ W^T + b ----------------
// 128x128 tile, BK=32 double-buffered, 1 barrier/iter prefetch pipeline.
// z=0 -> Qb (pre-scaled by QSCALE), z=1 -> Kb,
// z=2 -> Vt [b][h][d][seq] via LDS transpose, PRE-MASKED by mask[key]
__global__ __launch_bounds__(256, 3) void gemm_qkv(
    const unsigned short* __restrict__ Xb, const unsigned short* __restrict__ Wb,
    const float* __restrict__ bq, const float* __restrict__ bk, const float* __restrict__ bv,
    const int* __restrict__ mask,
    unsigned short* __restrict__ Qb, unsigned short* __restrict__ Kb,
    unsigned short* __restrict__ Vt)
{
  __shared__ alignas(16) unsigned short LB[16384];  // A dbuf @0/4096, B dbuf @8192/12288 (shorts)
  const int t = threadIdx.x;
  const int w = t >> 6, l = t & 63;
  const int lm = l & 15, lq = l >> 4;
  const int z = blockIdx.z;
  const size_t m0 = (size_t)blockIdx.y * 128;
  const size_t n0 = (size_t)blockIdx.x * 128;
  const unsigned short* W = Wb + (size_t)z * (1024 * 1024);
  const float* bias = (z == 0) ? bq : ((z == 1) ? bk : bv);
  const float sc = (z == 0) ? QSCALE : 1.0f;

  // staging: chunk c (16B) at LDS chunk-slot c; holds global (row=c>>2, kq=(c&3)^((row>>1)&3))
  const int c0 = t, c1 = 256 + t;
  const int row0 = c0 >> 2, row1 = c1 >> 2;
  const int kq0 = (c0 & 3) ^ ((row0 >> 1) & 3);
  const int kq1 = (c1 & 3) ^ ((row1 >> 1) & 3);
  const unsigned short* gA0 = Xb + (m0 + row0) * 1024 + kq0 * 8;
  const unsigned short* gA1 = Xb + (m0 + row1) * 1024 + kq1 * 8;
  const unsigned short* gB0 = W + (n0 + row0) * 1024 + kq0 * 8;
  const unsigned short* gB1 = W + (n0 + row1) * 1024 + kq1 * 8;
  const int la0 = (0 * 256 + w * 64) * 8;
  const int la1 = (1 * 256 + w * 64) * 8;

  const int wr = (w >> 1) * 64, wc = (w & 1) * 64;
  const int sw = (lq ^ ((lm >> 1) & 3)) * 8;
  floatx4 acc[4][4] = {};

  GLDS(gA0, LB + la0);
  GLDS(gA1, LB + la1);
  GLDS(gB0, LB + 8192 + la0);
  GLDS(gB1, LB + 8192 + la1);
  __syncthreads();

  for (int it = 0; it < 32; ++it) {
    const int cur = it & 1;
    if (it < 31) {
      const int kn = (it + 1) * 32;
      const int nb = (cur ^ 1) * 4096;
      GLDS(gA0 + kn, LB + nb + la0);
      GLDS(gA1 + kn, LB + nb + la1);
      GLDS(gB0 + kn, LB + 8192 + nb + la0);
      GLDS(gB1 + kn, LB + 8192 + nb + la1);
    }
    const unsigned short* Ab = LB + cur * 4096;
    const unsigned short* Bb = LB + 8192 + cur * 4096;
    bf16x8 af[4], bfr[4];
#pragma unroll
    for (int i = 0; i < 4; i++) af[i] = ldb8(Ab + (wr + i * 16 + lm) * 32 + sw);
#pragma unroll
    for (int j = 0; j < 4; j++) bfr[j] = ldb8(Bb + (wc + j * 16 + lm) * 32 + sw);
#pragma unroll
    for (int i = 0; i < 4; i++)
#pragma unroll
      for (int j = 0; j < 4; j++)
        acc[i][j] = __builtin_amdgcn_mfma_f32_16x16x32_bf16(af[i], bfr[j], acc[i][j], 0, 0, 0);
    __syncthreads();
  }

  // epilogue: C/D layout col=lane&15, row=quad*4+r
  if (z < 2) {
    unsigned short* dst = (z == 0) ? Qb : Kb;
#pragma unroll
    for (int j = 0; j < 4; j++) {
      const int ncol = (int)n0 + wc + j * 16 + lm;
      const float bval = bias[ncol];
#pragma unroll
      for (int i = 0; i < 4; i++)
#pragma unroll
        for (int r = 0; r < 4; r++) {
          const int mrow = (int)m0 + wr + i * 16 + lq * 4 + r;
          dst[(size_t)mrow * 1024 + ncol] = f2bf((acc[i][j][r] + bval) * sc);
        }
    }
  } else {
    // V: pre-mask rows by mask[key], transpose 128x128 through LDS, coalesced Vt stores
    float mk[4][4];
#pragma unroll
    for (int i = 0; i < 4; i++)
#pragma unroll
      for (int r = 0; r < 4; r++)
        mk[i][r] = (float)mask[(int)m0 + wr + i * 16 + lq * 4 + r];
#pragma unroll
    for (int j = 0; j < 4; j++) {
      const int nl = wc + j * 16 + lm;
      const float bval = bias[(int)n0 + nl];
#pragma unroll
      for (int i = 0; i < 4; i++)
#pragma unroll
        for (int r = 0; r < 4; r++) {
          const int ml = wr + i * 16 + lq * 4 + r;
          LB[nl * 128 + ((((ml >> 3) ^ (nl & 15)) * 8) | (ml & 7))] =
              f2bf((acc[i][j][r] + bval) * mk[i][r]);
        }
    }
    __syncthreads();
    const int nl = t >> 1, hf = t & 1;
    const int ncol = (int)n0 + nl;
    const int hh = ncol >> 6, dc = ncol & 63;
    const int bb = (int)(m0 >> 11);
    const int s0c = ((int)m0 & 2047) + hf * 64;
    unsigned short* dstp = Vt + (size_t)((bb * 16 + hh) * 64 + dc) * SEQ + s0c;
#pragma unroll
    for (int u = 0; u < 8; ++u) {
      const int phys = (hf * 8 + u) ^ (nl & 15);
      *(uintx4*)(dstp + u * 8) = *(const uintx4*)(LB + nl * 128 + phys * 8);
    }
  }
}

// ---------------- flash attention: P transposed in-register (no P LDS) ----------------
// grid 512, block 256 (4 waves x 32 q = 128 q/block). pp=bid&31 -> (b,head).
// S^T = K·Q^T (lane-local rows). C-layout->A-layout for P via one 64-bit
// __shfl_xor(32) per chunk + selects (half-wave pair exchange). LDS = K/V dbuf
// + mask frag buffer = 36 KB -> 3-4 blocks/CU. Denominator: tacc += P·mask01.
__global__ __launch_bounds__(256, 3) void attn(
    const unsigned short* __restrict__ Qb, const unsigned short* __restrict__ Kb,
    const unsigned short* __restrict__ Vt, const unsigned short* __restrict__ mb01,
    float* __restrict__ out)
{
  __shared__ alignas(16) unsigned short Klds[2][4096];  // [key][d], chunk-XOR (16 KB)
  __shared__ alignas(16) unsigned short Vlds[2][4096];  // [d][key], chunk-XOR (16 KB)
  __shared__ alignas(16) unsigned short Mb[2048];       // mask01 bf16 (4 KB)

  const int t = threadIdx.x, w = t >> 6, l = t & 63;
  const int ln = l & 31, h = l >> 5;
  const int bid = blockIdx.x;
  const int pp = bid & 31;
  const int b = pp >> 4, head = pp & 15;
  const int q0w = (bid >> 5) * 128 + w * 32;
  const int hoff = head * 64;

  // staging: chunk L = w*128 + s2*64 + l -> row L>>3, phys L&7; global chunk = (l&7)^(l>>3)
  const int sr = l >> 3;
  const int gc = (l & 7) ^ sr;
  const unsigned short* gK[2]; const unsigned short* gV[2];
#pragma unroll
  for (int s2 = 0; s2 < 2; ++s2) {
    const int row = w * 16 + s2 * 8 + sr;
    gK[s2] = Kb + (size_t)(b * SEQ + row) * DM + hoff + gc * 8;
    gV[s2] = Vt + (size_t)((b * NH + head) * 64 + row) * SEQ + gc * 8;
  }

  // stage tile 0 into buffer 0
#pragma unroll
  for (int s2 = 0; s2 < 2; ++s2) {
    GLDS(gK[s2], &Klds[0][(w * 128 + s2 * 64) * 8]);
    GLDS(gV[s2], &Vlds[0][(w * 128 + s2 * 64) * 8]);
  }

  // mask01 -> LDS (2048 bf16 = 4 KB)
  ((uintx4*)Mb)[t] = ((const uintx4*)(mb01 + b * SEQ))[t];

  // Q B-frags (n=q=ln, k=d)
  const unsigned short* Qbase = Qb + (size_t)(b * SEQ + q0w + ln) * DM + hoff + h * 8;
  bf16x8 qf[4];
#pragma unroll
  for (int c = 0; c < 4; ++c) qf[c] = ldb8(Qbase + c * 16);

  // frag-read swizzled chunk offsets: phys chunk = (2c+h) ^ (ln&7)
  const int cc = (ln >> 1) & 3, hb = h ^ (ln & 1);
  int xoff[4];
#pragma unroll
  for (int c = 0; c < 4; ++c) xoff[c] = (c ^ cc) * 16 + hb * 8;

  floatx16 oacc[2] = {};
  floatx16 tacc = {};   // denominator accumulator: rows match oacc rows

  __syncthreads();

  for (int kt = 0; kt < 32; ++kt) {
    const int cur = kt & 1;
    if (kt < 31) {   // prefetch next 64-key tile into the other buffer
      const int k0n = (kt + 1) * 64;
#pragma unroll
      for (int s2 = 0; s2 < 2; ++s2) {
        GLDS(gK[s2] + (size_t)k0n * DM, &Klds[cur ^ 1][(w * 128 + s2 * 64) * 8]);
        GLDS(gV[s2] + k0n,              &Vlds[cur ^ 1][(w * 128 + s2 * 64) * 8]);
      }
    }
    const unsigned short* Kc = &Klds[cur][ln * 64];
    const unsigned short* Vc = &Vlds[cur][ln * 64];

    // S^T = K · Q^T  (rows=keys, cols=q)
    floatx16 s[2] = {};
#pragma unroll
    for (int c = 0; c < 4; ++c) {
      s[0] = __builtin_amdgcn_mfma_f32_32x32x16_bf16(ldb8(Kc + xoff[c]),        qf[c], s[0], 0, 0, 0);
      s[1] = __builtin_amdgcn_mfma_f32_32x32x16_bf16(ldb8(Kc + 2048 + xoff[c]), qf[c], s[1], 0, 0, 0);
    }

    // softmax numerators: p = exp2(s), packed to bf16x4 per (kb,g).
    // Lane (ln,h) holds P[q=ln][key = kb*32 + g*8 + h*4 + r].
    unsigned long long pk[2][4];
#pragma unroll
    for (int kb = 0; kb < 2; ++kb)
#pragma unroll
      for (int g = 0; g < 4; ++g) {
        union { bf16x4 v; unsigned long long u; } pu;
#pragma unroll
        for (int r = 0; r < 4; ++r) pu.v[r] = (__bf16)EXP2(s[kb][g * 4 + r]);
        pk[kb][g] = pu.u;
      }

    // C-layout -> A-layout in registers: half-wave pair exchange per chunk c.
    // pf[c] lane (ln,h) = P[q=ln][key = c*16 + h*8 + j], j=0..7.
    const int k0 = kt * 64;
#pragma unroll
    for (int c = 0; c < 4; ++c) {
      const int kb = c >> 1, ge = (c & 1) * 2, go = ge + 1;
      const unsigned long long snd = h ? pk[kb][ge] : pk[kb][go];
      const unsigned long long rcv =
          (unsigned long long)__shfl_xor((long long)snd, 32, 64);
      union { unsigned long long u[2]; bf16x8 v; } fu;
      fu.u[0] = h ? rcv : pk[kb][ge];
      fu.u[1] = h ? pk[kb][go] : rcv;
      const bf16x8 pf = fu.v;

      // denominator: tacc += P · mask01 (broadcast B-frag from LDS)
      const bf16x8 mfr = ldb8(Mb + k0 + c * 16 + h * 8);
      tacc = __builtin_amdgcn_mfma_f32_32x32x16_bf16(pf, mfr, tacc, 0, 0, 0);
      // O += P · V (V pre-masked)
      oacc[0] = __builtin_amdgcn_mfma_f32_32x32x16_bf16(pf, ldb8(Vc + xoff[c]),        oacc[0], 0, 0, 0);
      oacc[1] = __builtin_amdgcn_mfma_f32_32x32x16_bf16(pf, ldb8(Vc + 2048 + xoff[c]), oacc[1], 0, 0, 0);
    }
    __syncthreads();   // drains prefetch issued one full tile of compute ago
  }

  // finalize: tacc[r] holds the denominator for row rq at every lane
  float* obase = out + (size_t)(b * SEQ + q0w) * DM + hoff;
#pragma unroll
  for (int r = 0; r < 16; ++r) {
    const int rq = (r & 3) + 8 * (r >> 2) + 4 * h;
    const float iv = __builtin_amdgcn_rcpf(tacc[r]);
    obase[(size_t)rq * DM + ln]      = oacc[0][r] * iv;
    obase[(size_t)rq * DM + 32 + ln] = oacc[1][r] * iv;
  }
}

// ---------------- launch ----------------
extern "C" void kernel_launch(void* const* d_in, const int* in_sizes, int n_in,
                              void* d_out, int out_size, void* d_ws, size_t ws_size,
                              hipStream_t stream) {
  const float* x   = (const float*)d_in[0];
  const int*   msk = (const int*)d_in[1];
  const float* Wq  = (const float*)d_in[2];
  const float* bq  = (const float*)d_in[3];
  const float* Wk  = (const float*)d_in[4];
  const float* bk  = (const float*)d_in[5];
  const float* Wv  = (const float*)d_in[6];
  const float* bv  = (const float*)d_in[7];
  float* out = (float*)d_out;

  unsigned short* ws = (unsigned short*)d_ws;
  unsigned short* Xb = ws;                               // [4096][1024]
  unsigned short* Wb = Xb + (size_t)4096 * 1024;         // [3][1024][1024]
  unsigned short* Qb = Wb + (size_t)3 * 1024 * 1024;     // [4096][1024], pre-scaled
  unsigned short* Kb = Qb + (size_t)4096 * 1024;         // [4096][1024]
  unsigned short* Vt = Kb + (size_t)4096 * 1024;         // [2][16][64][2048], pre-masked
  unsigned short* mb01 = Vt + (size_t)4096 * 1024;       // [2][2048] bf16 {0,1}

  prep<<<7184, 256, 0, stream>>>(x, Wq, Wk, Wv, msk, Xb, Wb, mb01);

  gemm_qkv<<<dim3(8, 32, 3), 256, 0, stream>>>(Xb, Wb, bq, bk, bv, msk, Qb, Kb, Vt);

  attn<<<512, 256, 0, stream>>>(Qb, Kb, Vt, mb01, out);
}